// Round 4
// baseline (1151.523 us; speedup 1.0000x reference)
//
#include <hip/hip_runtime.h>
#include <math.h>

// PQLayer forward, MI355X — R11: fused, 4 rows/thread, single cohort.
//   x: (B,512) fp32   C: (64,256,8) fp32
//   out0 x_hat (B,512) = C[m,k*,:]   out1 codes (B,64,256) = one_hot(k*)
//
// Model: dur = fill(~707us harness poison) + kernel + gaps. R10 kernel
// residue ~440us vs ~181us HBM floor. Cost split: broadcast ds_read_b128
// k-loop ~82us/cohort (paid PER WAVE, amortized over 1 row/thread) + codes
// write ~81us/cohort, phase-locked x 2 cohorts (4096 blocks, 8/CU).
//
// R11: 4 rows/thread -> 1024 blocks = ONE cohort (4 blocks/CU, 16 waves/CU).
//   - same 2 ds_read_b128/k feed 4 independent dot chains: LDS port /4 (~41us)
//   - VALU ~32us overlaps LDS across waves (different pipes)
//   - single cohort deletes one full argmax<->write serialization + tail
// Bit-exact: per-row tree unchanged (P=xa*ca, Q=xb*cb, T=P+Q,
// dot=(T.x+T.y)+(T.z+T.w), contract off, strict > = first-max); multi-chain
// row sharing is the same construction as R8 (passed, absmax 0.0); one-hot
// writer identical 4-compare form, remapped to 1024 rows/block.

#define B_SZ   16384
#define FEAT   512
#define M_SZ   64
#define K_SZ   256
#define D_SZ   8

typedef float v4f __attribute__((ext_vector_type(4)));

// 1024 blocks x 256 threads; block = (m, 1024 b-rows); thread = rows
// base, base+256, base+512, base+768.
__global__ __launch_bounds__(256) void pq_fused(
    const float* __restrict__ x,
    const float* __restrict__ C,
    float* __restrict__ xhat,
    float* __restrict__ codes)
{
#pragma clang fp contract(off)   // np einsum: separate product roundings, no FMA

    const int t     = threadIdx.x;
    const int m     = blockIdx.x & (M_SZ - 1);   // block-uniform m
    const int chunk = blockIdx.x >> 6;           // 0..15
    const int base  = (chunk << 10) | t;         // global row of local row t

    __shared__ v4f Cs[K_SZ * 2];            // 8KB; rows k: (d0..3),(d4..7)
    __shared__ unsigned char lbk[1024];     // bestk per local row

    // ---- 1. stage C[m]: thread t copies row t (32B), coalesced 8KB ----
    {
        const v4f* src = (const v4f*)(C + (size_t)m * (K_SZ * D_SZ)) + (t << 1);
        Cs[(t << 1) | 0] = src[0];
        Cs[(t << 1) | 1] = src[1];
    }

    // x slices for the 4 rows (row stride 256 rows = 256*FEAT floats)
    const float* xp0 = x + (size_t)base * FEAT + m * D_SZ;
    const float* xp1 = xp0 + (size_t)256 * FEAT;
    const float* xp2 = xp1 + (size_t)256 * FEAT;
    const float* xp3 = xp2 + (size_t)256 * FEAT;
    const v4f xa0 = ((const v4f*)xp0)[0], xb0 = ((const v4f*)xp0)[1];
    const v4f xa1 = ((const v4f*)xp1)[0], xb1 = ((const v4f*)xp1)[1];
    const v4f xa2 = ((const v4f*)xp2)[0], xb2 = ((const v4f*)xp2)[1];
    const v4f xa3 = ((const v4f*)xp3)[0], xb3 = ((const v4f*)xp3)[1];

    __syncthreads();

    // ---- 2. argmax over k: 4 independent chains share each ca/cb ----
    float best0 = -INFINITY, best1 = -INFINITY;
    float best2 = -INFINITY, best3 = -INFINITY;
    int   bk0 = 0, bk1 = 0, bk2 = 0, bk3 = 0;

#pragma unroll 2
    for (int k = 0; k < K_SZ; ++k) {
        const v4f ca = Cs[(k << 1) | 0];   // uniform addr -> broadcast
        const v4f cb = Cs[(k << 1) | 1];

        v4f P0 = xa0 * ca, Q0 = xb0 * cb, T0 = P0 + Q0;
        float d0 = (T0.x + T0.y) + (T0.z + T0.w);
        v4f P1 = xa1 * ca, Q1 = xb1 * cb, T1 = P1 + Q1;
        float d1 = (T1.x + T1.y) + (T1.z + T1.w);
        v4f P2 = xa2 * ca, Q2 = xb2 * cb, T2 = P2 + Q2;
        float d2 = (T2.x + T2.y) + (T2.z + T2.w);
        v4f P3 = xa3 * ca, Q3 = xb3 * cb, T3 = P3 + Q3;
        float d3 = (T3.x + T3.y) + (T3.z + T3.w);

        if (d0 > best0) { best0 = d0; bk0 = k; }  // strict >: first max
        if (d1 > best1) { best1 = d1; bk1 = k; }
        if (d2 > best2) { best2 = d2; bk2 = k; }
        if (d3 > best3) { best3 = d3; bk3 = k; }
    }

    // ---- 3. xhat gather from LDS copy (same bits as global C) ----
    {
        float* xh0 = xhat + (size_t)base * FEAT + m * D_SZ;
        ((v4f*)xh0)[0] = Cs[(bk0 << 1) | 0];
        ((v4f*)xh0)[1] = Cs[(bk0 << 1) | 1];
        float* xh1 = xh0 + (size_t)256 * FEAT;
        ((v4f*)xh1)[0] = Cs[(bk1 << 1) | 0];
        ((v4f*)xh1)[1] = Cs[(bk1 << 1) | 1];
        float* xh2 = xh1 + (size_t)256 * FEAT;
        ((v4f*)xh2)[0] = Cs[(bk2 << 1) | 0];
        ((v4f*)xh2)[1] = Cs[(bk2 << 1) | 1];
        float* xh3 = xh2 + (size_t)256 * FEAT;
        ((v4f*)xh3)[0] = Cs[(bk3 << 1) | 0];
        ((v4f*)xh3)[1] = Cs[(bk3 << 1) | 1];
    }

    // ---- 4. share bestk within block ----
    lbk[t]       = (unsigned char)bk0;
    lbk[t + 256] = (unsigned char)bk1;
    lbk[t + 512] = (unsigned char)bk2;
    lbk[t + 768] = (unsigned char)bk3;
    __syncthreads();

    // ---- 5. codes: 1024 rows x 1KB one-hot, coalesced wave-stores ----
    const int w     = t >> 6;        // wave 0..3
    const int lane  = t & 63;
    const int lane4 = lane << 2;

#pragma unroll 4
    for (int j = 0; j < 256; ++j) {
        const int i  = (j << 2) | w;               // local row 0..1023
        const int kk = (int)lbk[i];                // LDS broadcast (uniform)
        float4 v;
        v.x = (kk == lane4 + 0) ? 1.0f : 0.0f;
        v.y = (kk == lane4 + 1) ? 1.0f : 0.0f;
        v.z = (kk == lane4 + 2) ? 1.0f : 0.0f;
        v.w = (kk == lane4 + 3) ? 1.0f : 0.0f;
        // float4 index: b_row*4096 + m*64 + lane  (1KB contiguous per wave)
        const size_t f4 = ((size_t)((chunk << 10) | i) << 12) + (m << 6) + lane;
        ((float4*)codes)[f4] = v;
    }
}

extern "C" void kernel_launch(void* const* d_in, const int* in_sizes, int n_in,
                              void* d_out, int out_size, void* d_ws, size_t ws_size,
                              hipStream_t stream)
{
    const float* x = (const float*)d_in[0];
    const float* C = (const float*)d_in[1];
    float* xhat  = (float*)d_out;                           // (B, 512)
    float* codes = (float*)d_out + (size_t)B_SZ * FEAT;     // (B, 64, 256)

    hipLaunchKernelGGL(pq_fused, dim3(1024), dim3(256), 0, stream,
                       x, C, xhat, codes);
}